// Round 10
// baseline (608.344 us; speedup 1.0000x reference)
//
#include <hip/hip_runtime.h>
#include <cstdint>
#include <cstddef>

typedef unsigned int uint32;
typedef unsigned short ushort16;   // scalar ushort (bf16 storage)
typedef __attribute__((ext_vector_type(8))) short short8;
typedef __attribute__((ext_vector_type(4))) float floatx4;

__device__ __forceinline__ ushort16 f2bf(float f) {
    uint32 u = __builtin_bit_cast(uint32, f);
    uint32 r = (u + 0x7fffu + ((u >> 16) & 1u)) >> 16;   // RNE
    return (ushort16)r;
}
__device__ __forceinline__ float bf2f(ushort16 h) {
    uint32 u = ((uint32)h) << 16;
    return __builtin_bit_cast(float, u);
}

#define PBS 4096

// ---------------- graph prep: 3-kernel bucketed CSR build ----------------
__global__ __launch_bounds__(256) void bucket_hist_kernel(
    const int* __restrict__ dst, int* __restrict__ bcnt, int E, int NBUCK) {
    __shared__ int l[512];
    int t = threadIdx.x;
    for (int b = t; b < NBUCK; b += 256) l[b] = 0;
    __syncthreads();
    int e0 = blockIdx.x * PBS;
    int e1 = e0 + PBS; if (e1 > E) e1 = E;
    for (int j = e0 + t; j < e1; j += 256)
        atomicAdd(&l[dst[j] >> 8], 1);
    __syncthreads();
    for (int b = t; b < NBUCK; b += 256) {
        int c = l[b];
        if (c) atomicAdd(&bcnt[b], c);
    }
}

__global__ __launch_bounds__(256) void bucket_scan_kernel(
    const int* __restrict__ bcnt, int* __restrict__ bucketOff,
    int* __restrict__ cursorA, int NBUCK, int E) {
    __shared__ int a[512], b[512];
    int t = threadIdx.x;
    a[t] = (t < NBUCK) ? bcnt[t] : 0;
    a[t + 256] = (t + 256 < NBUCK) ? bcnt[t + 256] : 0;
    __syncthreads();
    int* cur = a; int* nxt = b;
    for (int o = 1; o < 512; o <<= 1) {
#pragma unroll
        for (int i = t; i < 512; i += 256)
            nxt[i] = cur[i] + ((i >= o) ? cur[i - o] : 0);
        __syncthreads();
        int* tmp = cur; cur = nxt; nxt = tmp;
    }
#pragma unroll
    for (int i = t; i < 512; i += 256) {
        if (i <= NBUCK) {
            int off = (i == 0) ? 0 : cur[i - 1];
            bucketOff[i] = off;
            if (i < NBUCK) cursorA[i] = off;
        }
    }
    if (t == 0) bucketOff[NBUCK] = E;
}

__global__ __launch_bounds__(256) void bucket_partition_kernel(
    const int* __restrict__ src, const int* __restrict__ dst,
    int* __restrict__ cursorA, uint32* __restrict__ ebuf, int E, int NBUCK) {
    __shared__ int lbase[512];
    int tid = threadIdx.x;
    for (int b = tid; b < NBUCK; b += 256) lbase[b] = 0;
    __syncthreads();
    int e0 = blockIdx.x * PBS;
    int e1 = e0 + PBS; if (e1 > E) e1 = E;
    for (int j = e0 + tid; j < e1; j += 256)
        atomicAdd(&lbase[dst[j] >> 8], 1);
    __syncthreads();
    for (int b = tid; b < NBUCK; b += 256) {
        int c = lbase[b];
        lbase[b] = c ? atomicAdd(&cursorA[b], c) : 0;
    }
    __syncthreads();
    for (int j = e0 + tid; j < e1; j += 256) {
        int d = dst[j];
        int p = atomicAdd(&lbase[d >> 8], 1);
        ebuf[p] = ((uint32)src[j] << 8) | (uint32)(d & 255);
    }
}

__global__ __launch_bounds__(256) void bucket_build_kernel(
    const uint32* __restrict__ ebuf, const int* __restrict__ bucketOff,
    int* __restrict__ row_ptr, float* __restrict__ degf,
    int* __restrict__ csr, int N, int E) {
    __shared__ int ldeg[256];
    __shared__ int lscan[256];
    __shared__ int lcur[256];
    int b = blockIdx.x, t = threadIdx.x;
    int n0 = b << 8;
    int s = bucketOff[b], e = bucketOff[b + 1];
    ldeg[t] = 0;
    __syncthreads();
    for (int j = s + t; j < e; j += 256)
        atomicAdd(&ldeg[ebuf[j] & 255u], 1);
    __syncthreads();
    int v = ldeg[t];
    lscan[t] = v;
    __syncthreads();
    for (int off = 1; off < 256; off <<= 1) {
        int x = (t >= off) ? lscan[t - off] : 0;
        __syncthreads();
        lscan[t] += x;
        __syncthreads();
    }
    int excl = lscan[t] - v;
    int node = n0 + t;
    if (node < N) {
        row_ptr[node] = s + excl;
        degf[node] = (float)(v > 0 ? v : 1);
    }
    lcur[t] = s + excl;
    __syncthreads();
    for (int j = s + t; j < e; j += 256) {
        uint32 en = ebuf[j];
        int p = atomicAdd(&lcur[en & 255u], 1);
        csr[p] = (int)(en >> 8);
    }
    if (b == 0 && t == 0) row_ptr[N] = E;
}

// ---------------- dtype prep ----------------
__global__ void conv_bf16_kernel(const float* __restrict__ x, ushort16* __restrict__ y, int n8) {
    int i = blockIdx.x * blockDim.x + threadIdx.x;
    if (i >= n8) return;
    const float4 a = *(const float4*)(x + (size_t)i * 8);
    const float4 b = *(const float4*)(x + (size_t)i * 8 + 4);
    uint4 o;
    o.x = (uint32)f2bf(a.x) | ((uint32)f2bf(a.y) << 16);
    o.y = (uint32)f2bf(a.z) | ((uint32)f2bf(a.w) << 16);
    o.z = (uint32)f2bf(b.x) | ((uint32)f2bf(b.y) << 16);
    o.w = (uint32)f2bf(b.z) | ((uint32)f2bf(b.w) << 16);
    *(uint4*)(y + (size_t)i * 8) = o;
}

// All six weight matrices [K][M] fp32 -> transposed padded [n=128][k=128]
// bf16 hi + lo, in one launch. mat = blockIdx.x/64: (layer, s/n).
__global__ void prep_w_all_kernel(
    const float* __restrict__ W0s, const float* __restrict__ W0n,
    const float* __restrict__ W1s, const float* __restrict__ W1n,
    const float* __restrict__ W2s, const float* __restrict__ W2n,
    ushort16* __restrict__ Whi, ushort16* __restrict__ Wlo) {
    int mat = blockIdx.x >> 6;
    int idx = (blockIdx.x & 63) * 256 + threadIdx.x;
    const float* Wt[6] = {W0s, W0n, W1s, W1n, W2s, W2n};
    const int Kt[6] = {128, 128, 128, 128, 118, 118};
    const int Mt[6] = {128, 128, 118, 118, 103, 103};
    int n = idx >> 7, k = idx & 127;
    int K = Kt[mat], M = Mt[mat];
    float w = (k < K && n < M) ? Wt[mat][(size_t)k * M + n] : 0.f;
    ushort16 h = f2bf(w);
    float lo = w - bf2f(h);
    Whi[(size_t)mat * 16384 + idx] = h;
    Wlo[(size_t)mat * 16384 + idx] = f2bf(lo);
}

// ---------------- bf16 CSR pre-aggregation (layers 1-3) ----------------
template<int UNROLL>
__global__ __launch_bounds__(256) void aggregate_pre_kernel(
    const ushort16* __restrict__ h,
    const int* __restrict__ row_ptr, const int* __restrict__ csr,
    const float* __restrict__ degf, ushort16* __restrict__ aggH, int N) {
    int wid = threadIdx.x >> 6;
    int lane = threadIdx.x & 63;
    int node = blockIdx.x * 4 + wid;
    if (node >= N) return;
    int s = row_ptr[node], e = row_ptr[node + 1];
    int c = lane & 15;
    int eo = lane >> 4;
    float aLo[4] = {}, aHi[4] = {};
    int j = s + eo;
    for (; j + (UNROLL - 1) * 4 < e; j += UNROLL * 4) {
        uint4 v[UNROLL];
#pragma unroll
        for (int u = 0; u < UNROLL; ++u) {
            int src_n = csr[j + u * 4];
            v[u] = *(const uint4*)(h + ((size_t)src_n << 7) + (c << 3));
        }
#pragma unroll
        for (int u = 0; u < UNROLL; ++u) {
            uint32 w[4] = {v[u].x, v[u].y, v[u].z, v[u].w};
#pragma unroll
            for (int p = 0; p < 4; ++p) {
                aLo[p] += __builtin_bit_cast(float, w[p] << 16);
                aHi[p] += __builtin_bit_cast(float, w[p] & 0xffff0000u);
            }
        }
    }
    for (; j < e; j += 4) {
        int src_n = csr[j];
        uint4 v = *(const uint4*)(h + ((size_t)src_n << 7) + (c << 3));
        uint32 w[4] = {v.x, v.y, v.z, v.w};
#pragma unroll
        for (int p = 0; p < 4; ++p) {
            aLo[p] += __builtin_bit_cast(float, w[p] << 16);
            aHi[p] += __builtin_bit_cast(float, w[p] & 0xffff0000u);
        }
    }
#pragma unroll
    for (int m = 16; m < 64; m <<= 1) {
#pragma unroll
        for (int p = 0; p < 4; ++p) {
            aLo[p] += __shfl_xor(aLo[p], m, 64);
            aHi[p] += __shfl_xor(aHi[p], m, 64);
        }
    }
    if (lane < 16) {
        float inv = 1.f / degf[node];
        uint4 ov;
        ov.x = (uint32)f2bf(aLo[0] * inv) | ((uint32)f2bf(aHi[0] * inv) << 16);
        ov.y = (uint32)f2bf(aLo[1] * inv) | ((uint32)f2bf(aHi[1] * inv) << 16);
        ov.z = (uint32)f2bf(aLo[2] * inv) | ((uint32)f2bf(aHi[2] * inv) << 16);
        ov.w = (uint32)f2bf(aLo[3] * inv) | ((uint32)f2bf(aHi[3] * inv) << 16);
        *(uint4*)(aggH + ((size_t)node << 7) + (c << 3)) = ov;
    }
}

// ---------------- fused MFMA layer (layers 1-3), v3 ----------------
// out = bf16( relu( h@Ws + aggH@Wn + bias ) ).
// R9 post-mortem: LDS-free B loads from L2 are latency-bound at 2 waves/SIMD.
// v3 = R8's LDS staging, but block covers 256 rows (wave = 4 row-groups of
// 16): same 32KB staged per k0 amortized over 4x the MFMA, and B-fragments
// are reused from registers across row-groups (ds_read:MFMA = 1:4 vs R8 1:1).
#define RS 40   // LDS row stride in ushorts (80B, 16B-aligned, bank-spread)
__global__ __launch_bounds__(256) void mfma_fused_kernel(
    const ushort16* __restrict__ A, const ushort16* __restrict__ G,
    const ushort16* __restrict__ Whi, const ushort16* __restrict__ Wlo,
    const float* __restrict__ bias,
    ushort16* __restrict__ Out, int N, int M) {
    __shared__ ushort16 Bs[4][128 * RS];
    const int tid = threadIdx.x;
    const int wave = tid >> 6;
    const int lane = tid & 63;
    const int quad = lane >> 4;
    const int m16 = lane & 15;
    // [0]=Ws_hi, [1]=Ws_lo, [2]=Wn_hi, [3]=Wn_lo
    const ushort16* Wg[4] = {Whi, Wlo, Whi + 16384, Wlo + 16384};

    floatx4 acc[4][8] = {};                 // [rowgroup][ntile] = 128 VGPRs

    const int wbase = blockIdx.x * 256 + wave * 64;   // wave covers 64 rows
    const int sn = tid >> 1, shalf = tid & 1;          // staging: row n, 16-ushort half

    for (int k0 = 0; k0 < 128; k0 += 32) {
#pragma unroll
        for (int mat = 0; mat < 4; ++mat) {
            const ushort16* g = Wg[mat] + (size_t)sn * 128 + k0 + shalf * 16;
            uint4 v0 = *(const uint4*)(g);
            uint4 v1 = *(const uint4*)(g + 8);
            ushort16* d = &Bs[mat][sn * RS + shalf * 16];
            *(uint4*)(d) = v0;
            *(uint4*)(d + 8) = v1;
        }
        // A/G fragments for this k0 (A[m=m16][k=quad*8+j]), 4 row-groups
        short8 af[4], gf[4];
#pragma unroll
        for (int i = 0; i < 4; ++i) {
            int row = wbase + i * 16 + m16;
            if (row >= N) row = N - 1;      // clamp: stores guarded below
            af[i] = *(const short8*)(A + (size_t)row * 128 + k0 + quad * 8);
            gf[i] = *(const short8*)(G + (size_t)row * 128 + k0 + quad * 8);
        }
        __syncthreads();
#pragma unroll
        for (int t = 0; t < 8; ++t) {
            int nb = t * 16 + m16;
            short8 bsh = *(const short8*)(&Bs[0][nb * RS + quad * 8]);
            short8 bsl = *(const short8*)(&Bs[1][nb * RS + quad * 8]);
            short8 bnh = *(const short8*)(&Bs[2][nb * RS + quad * 8]);
            short8 bnl = *(const short8*)(&Bs[3][nb * RS + quad * 8]);
#pragma unroll
            for (int i = 0; i < 4; ++i) {
                acc[i][t] = __builtin_amdgcn_mfma_f32_16x16x32_bf16(af[i], bsh, acc[i][t], 0, 0, 0);
                acc[i][t] = __builtin_amdgcn_mfma_f32_16x16x32_bf16(gf[i], bnh, acc[i][t], 0, 0, 0);
                acc[i][t] = __builtin_amdgcn_mfma_f32_16x16x32_bf16(af[i], bsl, acc[i][t], 0, 0, 0);
                acc[i][t] = __builtin_amdgcn_mfma_f32_16x16x32_bf16(gf[i], bnl, acc[i][t], 0, 0, 0);
            }
        }
        __syncthreads();
    }

    // D layout: row = quad*4 + reg, col = t*16 + m16
#pragma unroll
    for (int t = 0; t < 8; ++t) {
        int colt = t * 16 + m16;
        bool inc = (colt < M);
        float b = inc ? bias[colt] : 0.f;
#pragma unroll
        for (int i = 0; i < 4; ++i) {
            int rowBase = wbase + i * 16 + quad * 4;
#pragma unroll
            for (int r = 0; r < 4; ++r) {
                int row = rowBase + r;
                if (row < N) {
                    float v = inc ? fmaxf(acc[i][t][r] + b, 0.f) : 0.f;
                    Out[(size_t)row * 128 + colt] = f2bf(v);
                }
            }
        }
    }
}

// ---------------- layer 4: tiny GEMM (M=5) ----------------
__global__ __launch_bounds__(256) void gemm4_kernel(
    const ushort16* __restrict__ A, const float* __restrict__ ws,
    const float* __restrict__ wn, const float* __restrict__ b4,
    float* __restrict__ Cs, float* __restrict__ Cn, int N, int K, int M) {
    __shared__ float Wsh[520], Wnh[520];
    int tid = threadIdx.x;
    for (int i = tid; i < K * M; i += 256) { Wsh[i] = ws[i]; Wnh[i] = wn[i]; }
    __syncthreads();
    int node = blockIdx.x * 256 + tid;
    if (node >= N) return;
    const ushort16* row = A + ((size_t)node << 7);
    float s[5] = {}, n[5] = {};
    for (int c8 = 0; c8 * 8 < K; ++c8) {
        uint4 v = *(const uint4*)(row + c8 * 8);
        uint32 w[4] = {v.x, v.y, v.z, v.w};
#pragma unroll
        for (int j = 0; j < 8; ++j) {
            int k = c8 * 8 + j;
            if (k < K) {
                float a = (j & 1) ? __builtin_bit_cast(float, w[j >> 1] & 0xffff0000u)
                                  : __builtin_bit_cast(float, w[j >> 1] << 16);
#pragma unroll
                for (int m = 0; m < 5; ++m) {
                    s[m] += a * Wsh[k * 5 + m];
                    n[m] += a * Wnh[k * 5 + m];
                }
            }
        }
    }
    size_t o = (size_t)node * 8;
#pragma unroll
    for (int m = 0; m < 5; ++m) {
        Cs[o + m] = s[m] + b4[m];
        Cn[o + m] = n[m];
    }
#pragma unroll
    for (int m = 5; m < 8; ++m) { Cs[o + m] = 0.f; Cn[o + m] = 0.f; }
}

// ---------------- fp32 CSR aggregation (layer 4, stride 8) ----------------
template<int CPW, int UNROLL, int SLOG>
__global__ __launch_bounds__(256) void aggregate_fp32_kernel(
    const float* __restrict__ hs, const float* __restrict__ hn,
    const int* __restrict__ row_ptr, const int* __restrict__ csr,
    const float* __restrict__ degf, float* __restrict__ out, int N) {
    constexpr int EPI = 64 / CPW;
    int wid = threadIdx.x >> 6;
    int lane = threadIdx.x & 63;
    int node = blockIdx.x * 4 + wid;
    if (node >= N) return;
    int s = row_ptr[node], e = row_ptr[node + 1];
    int c = lane & (CPW - 1);
    int eo = lane / CPW;
    float4 acc = make_float4(0.f, 0.f, 0.f, 0.f);
    int j = s + eo;
    for (; j + (UNROLL - 1) * EPI < e; j += UNROLL * EPI) {
        float4 v[UNROLL];
#pragma unroll
        for (int u = 0; u < UNROLL; ++u) {
            int src_n = csr[j + u * EPI];
            v[u] = *(const float4*)(hn + ((size_t)src_n << SLOG) + (c << 2));
        }
#pragma unroll
        for (int u = 0; u < UNROLL; ++u) {
            acc.x += v[u].x; acc.y += v[u].y; acc.z += v[u].z; acc.w += v[u].w;
        }
    }
    for (; j < e; j += EPI) {
        int src_n = csr[j];
        float4 v = *(const float4*)(hn + ((size_t)src_n << SLOG) + (c << 2));
        acc.x += v.x; acc.y += v.y; acc.z += v.z; acc.w += v.w;
    }
#pragma unroll
    for (int m = CPW; m < 64; m <<= 1) {
        acc.x += __shfl_xor(acc.x, m, 64);
        acc.y += __shfl_xor(acc.y, m, 64);
        acc.z += __shfl_xor(acc.z, m, 64);
        acc.w += __shfl_xor(acc.w, m, 64);
    }
    if (lane < CPW) {
        float d = 1.f / degf[node];
        size_t o = ((size_t)node << SLOG) + (lane << 2);
        float4 hv = *(const float4*)(hs + o);
        float4 r;
        r.x = hv.x + acc.x * d;
        r.y = hv.y + acc.y * d;
        r.z = hv.z + acc.z * d;
        r.w = hv.w + acc.w * d;
        *(float4*)(out + o) = r;
    }
}

// ---------------- per-graph mean pool (stride 8) ----------------
__global__ __launch_bounds__(256) void pool_kernel(
    const float* __restrict__ h, float* __restrict__ out, int npg) {
    __shared__ float sh[4][5];
    int g = blockIdx.x;
    int t = threadIdx.x;
    float acc[5] = {0.f, 0.f, 0.f, 0.f, 0.f};
    int base = g * npg;
    for (int i = t; i < npg; i += 256) {
        const float* r = h + ((size_t)(base + i) << 3);
#pragma unroll
        for (int f = 0; f < 5; ++f) acc[f] += r[f];
    }
#pragma unroll
    for (int off = 32; off > 0; off >>= 1) {
#pragma unroll
        for (int f = 0; f < 5; ++f) acc[f] += __shfl_down(acc[f], off, 64);
    }
    int wid = t >> 6, lane = t & 63;
    if (lane == 0) {
#pragma unroll
        for (int f = 0; f < 5; ++f) sh[wid][f] = acc[f];
    }
    __syncthreads();
    if (t == 0) {
        float inv = 1.f / (float)npg;
#pragma unroll
        for (int f = 0; f < 5; ++f)
            out[g * 5 + f] = (sh[0][f] + sh[1][f] + sh[2][f] + sh[3][f]) * inv;
    }
}

extern "C" void kernel_launch(void* const* d_in, const int* in_sizes, int n_in,
                              void* d_out, int out_size, void* d_ws, size_t ws_size,
                              hipStream_t stream) {
    const float* in_feat = (const float*)d_in[0];
    const int* src = (const int*)d_in[1];
    const int* dst = (const int*)d_in[2];
    const int DIMS[5] = {128, 128, 118, 103, 5};
    const int N = in_sizes[0] / 128;
    const int E = in_sizes[1];
    const int G = out_size / 5;
    const int NBUCK = (N + 255) >> 8;   // 256-node dst buckets (<=512 for LDS)

    char* base = (char*)d_ws;
    size_t off = 0;
    auto carve = [&](size_t bytes) -> void* {
        off = (off + 255) & ~(size_t)255;
        void* p = base + off;
        off += bytes;
        return p;
    };
    int* bcnt = (int*)carve((size_t)NBUCK * 4);
    int* bucketOff = (int*)carve((size_t)(NBUCK + 1) * 4);
    int* cursorA = (int*)carve((size_t)NBUCK * 4);
    int* row_ptr = (int*)carve((size_t)(N + 1) * 4);
    float* degf = (float*)carve((size_t)N * 4);
    uint32* ebuf = (uint32*)carve((size_t)E * 4);
    int* csr = (int*)carve((size_t)E * 4);
    ushort16* buf0 = (ushort16*)carve((size_t)(N + 256) * 128 * 2);
    ushort16* buf1 = (ushort16*)carve((size_t)(N + 256) * 128 * 2);
    ushort16* aggH = (ushort16*)carve((size_t)(N + 256) * 128 * 2);
    ushort16* Whi = (ushort16*)carve((size_t)6 * 16384 * 2);
    ushort16* Wlo = (ushort16*)carve((size_t)6 * 16384 * 2);
    float* Cs4 = (float*)carve((size_t)N * 8 * 4);
    float* Cn4 = (float*)carve((size_t)N * 8 * 4);
    float* out4 = (float*)carve((size_t)N * 8 * 4);
    (void)n_in; (void)ws_size;

    // graph structure: bucket sizes -> offsets -> partition -> per-bucket build
    hipMemsetAsync(bcnt, 0, (size_t)NBUCK * 4, stream);
    bucket_hist_kernel<<<(E + PBS - 1) / PBS, 256, 0, stream>>>(dst, bcnt, E, NBUCK);
    bucket_scan_kernel<<<1, 256, 0, stream>>>(bcnt, bucketOff, cursorA, NBUCK, E);
    bucket_partition_kernel<<<(E + PBS - 1) / PBS, 256, 0, stream>>>(
        src, dst, cursorA, ebuf, E, NBUCK);
    bucket_build_kernel<<<NBUCK, 256, 0, stream>>>(
        ebuf, bucketOff, row_ptr, degf, csr, N, E);

    // dtype prep
    int n8 = N * 16;   // N*128/8
    conv_bf16_kernel<<<(n8 + 255) / 256, 256, 0, stream>>>(in_feat, buf0, n8);
    prep_w_all_kernel<<<6 * 64, 256, 0, stream>>>(
        (const float*)d_in[4], (const float*)d_in[5],
        (const float*)d_in[7], (const float*)d_in[8],
        (const float*)d_in[10], (const float*)d_in[11],
        Whi, Wlo);

    // layers 1-3: aggregate-first, then fused MFMA (256 rows/block)
    ushort16* hb[4] = {buf0, buf1, buf0, buf1};
    int gblocks = (N + 255) / 256;
    for (int l = 0; l < 3; ++l) {
        int M = DIMS[l + 1];
        const float* b = (const float*)d_in[6 + 3 * l];
        aggregate_pre_kernel<4><<<(N + 3) / 4, 256, 0, stream>>>(
            hb[l], row_ptr, csr, degf, aggH, N);
        mfma_fused_kernel<<<gblocks, 256, 0, stream>>>(
            hb[l], aggH, Whi + (size_t)l * 2 * 16384, Wlo + (size_t)l * 2 * 16384,
            b, hb[l + 1], N, M);
    }

    // layer 4 (aggregate-after: dout=5) + pool
    gemm4_kernel<<<(N + 255) / 256, 256, 0, stream>>>(
        hb[3], (const float*)d_in[13], (const float*)d_in[14], (const float*)d_in[15],
        Cs4, Cn4, N, DIMS[3], DIMS[4]);
    aggregate_fp32_kernel<2, 1, 3><<<(N + 3) / 4, 256, 0, stream>>>(
        Cs4, Cn4, row_ptr, csr, degf, out4, N);
    pool_kernel<<<G, 256, 0, stream>>>(out4, (float*)d_out, N / G);
}

// Round 11
// 518.405 us; speedup vs baseline: 1.1735x; 1.1735x over previous
//
#include <hip/hip_runtime.h>
#include <cstdint>
#include <cstddef>

typedef unsigned int uint32;
typedef unsigned short ushort16;   // scalar ushort (bf16 storage)
typedef __attribute__((ext_vector_type(8))) short short8;
typedef __attribute__((ext_vector_type(4))) float floatx4;

__device__ __forceinline__ ushort16 f2bf(float f) {
    uint32 u = __builtin_bit_cast(uint32, f);
    uint32 r = (u + 0x7fffu + ((u >> 16) & 1u)) >> 16;   // RNE
    return (ushort16)r;
}
__device__ __forceinline__ float bf2f(ushort16 h) {
    uint32 u = ((uint32)h) << 16;
    return __builtin_bit_cast(float, u);
}

#define PBS 4096

// ---------------- graph prep: 3-kernel bucketed CSR build ----------------
__global__ __launch_bounds__(256) void bucket_hist_kernel(
    const int* __restrict__ dst, int* __restrict__ bcnt, int E, int NBUCK) {
    __shared__ int l[512];
    int t = threadIdx.x;
    for (int b = t; b < NBUCK; b += 256) l[b] = 0;
    __syncthreads();
    int e0 = blockIdx.x * PBS;
    int e1 = e0 + PBS; if (e1 > E) e1 = E;
    for (int j = e0 + t; j < e1; j += 256)
        atomicAdd(&l[dst[j] >> 8], 1);
    __syncthreads();
    for (int b = t; b < NBUCK; b += 256) {
        int c = l[b];
        if (c) atomicAdd(&bcnt[b], c);
    }
}

__global__ __launch_bounds__(256) void bucket_scan_kernel(
    const int* __restrict__ bcnt, int* __restrict__ bucketOff,
    int* __restrict__ cursorA, int NBUCK, int E) {
    __shared__ int a[512], b[512];
    int t = threadIdx.x;
    a[t] = (t < NBUCK) ? bcnt[t] : 0;
    a[t + 256] = (t + 256 < NBUCK) ? bcnt[t + 256] : 0;
    __syncthreads();
    int* cur = a; int* nxt = b;
    for (int o = 1; o < 512; o <<= 1) {
#pragma unroll
        for (int i = t; i < 512; i += 256)
            nxt[i] = cur[i] + ((i >= o) ? cur[i - o] : 0);
        __syncthreads();
        int* tmp = cur; cur = nxt; nxt = tmp;
    }
#pragma unroll
    for (int i = t; i < 512; i += 256) {
        if (i <= NBUCK) {
            int off = (i == 0) ? 0 : cur[i - 1];
            bucketOff[i] = off;
            if (i < NBUCK) cursorA[i] = off;
        }
    }
    if (t == 0) bucketOff[NBUCK] = E;
}

__global__ __launch_bounds__(256) void bucket_partition_kernel(
    const int* __restrict__ src, const int* __restrict__ dst,
    int* __restrict__ cursorA, uint32* __restrict__ ebuf, int E, int NBUCK) {
    __shared__ int lbase[512];
    int tid = threadIdx.x;
    for (int b = tid; b < NBUCK; b += 256) lbase[b] = 0;
    __syncthreads();
    int e0 = blockIdx.x * PBS;
    int e1 = e0 + PBS; if (e1 > E) e1 = E;
    for (int j = e0 + tid; j < e1; j += 256)
        atomicAdd(&lbase[dst[j] >> 8], 1);
    __syncthreads();
    for (int b = tid; b < NBUCK; b += 256) {
        int c = lbase[b];
        lbase[b] = c ? atomicAdd(&cursorA[b], c) : 0;
    }
    __syncthreads();
    for (int j = e0 + tid; j < e1; j += 256) {
        int d = dst[j];
        int p = atomicAdd(&lbase[d >> 8], 1);
        ebuf[p] = ((uint32)src[j] << 8) | (uint32)(d & 255);
    }
}

__global__ __launch_bounds__(256) void bucket_build_kernel(
    const uint32* __restrict__ ebuf, const int* __restrict__ bucketOff,
    int* __restrict__ row_ptr, float* __restrict__ degf,
    int* __restrict__ csr, int N, int E) {
    __shared__ int ldeg[256];
    __shared__ int lscan[256];
    __shared__ int lcur[256];
    int b = blockIdx.x, t = threadIdx.x;
    int n0 = b << 8;
    int s = bucketOff[b], e = bucketOff[b + 1];
    ldeg[t] = 0;
    __syncthreads();
    for (int j = s + t; j < e; j += 256)
        atomicAdd(&ldeg[ebuf[j] & 255u], 1);
    __syncthreads();
    int v = ldeg[t];
    lscan[t] = v;
    __syncthreads();
    for (int off = 1; off < 256; off <<= 1) {
        int x = (t >= off) ? lscan[t - off] : 0;
        __syncthreads();
        lscan[t] += x;
        __syncthreads();
    }
    int excl = lscan[t] - v;
    int node = n0 + t;
    if (node < N) {
        row_ptr[node] = s + excl;
        degf[node] = (float)(v > 0 ? v : 1);
    }
    lcur[t] = s + excl;
    __syncthreads();
    for (int j = s + t; j < e; j += 256) {
        uint32 en = ebuf[j];
        int p = atomicAdd(&lcur[en & 255u], 1);
        csr[p] = (int)(en >> 8);
    }
    if (b == 0 && t == 0) row_ptr[N] = E;
}

// ---------------- dtype prep ----------------
__global__ void conv_bf16_kernel(const float* __restrict__ x, ushort16* __restrict__ y, int n8) {
    int i = blockIdx.x * blockDim.x + threadIdx.x;
    if (i >= n8) return;
    const float4 a = *(const float4*)(x + (size_t)i * 8);
    const float4 b = *(const float4*)(x + (size_t)i * 8 + 4);
    uint4 o;
    o.x = (uint32)f2bf(a.x) | ((uint32)f2bf(a.y) << 16);
    o.y = (uint32)f2bf(a.z) | ((uint32)f2bf(a.w) << 16);
    o.z = (uint32)f2bf(b.x) | ((uint32)f2bf(b.y) << 16);
    o.w = (uint32)f2bf(b.z) | ((uint32)f2bf(b.w) << 16);
    *(uint4*)(y + (size_t)i * 8) = o;
}

// All six weight matrices [K][M] fp32 -> transposed padded [n=128][k=128]
// bf16 hi + lo, in one launch. mat = blockIdx.x/64: (layer, s/n).
__global__ void prep_w_all_kernel(
    const float* __restrict__ W0s, const float* __restrict__ W0n,
    const float* __restrict__ W1s, const float* __restrict__ W1n,
    const float* __restrict__ W2s, const float* __restrict__ W2n,
    ushort16* __restrict__ Whi, ushort16* __restrict__ Wlo) {
    int mat = blockIdx.x >> 6;
    int idx = (blockIdx.x & 63) * 256 + threadIdx.x;
    const float* Wt[6] = {W0s, W0n, W1s, W1n, W2s, W2n};
    const int Kt[6] = {128, 128, 128, 128, 118, 118};
    const int Mt[6] = {128, 128, 118, 118, 103, 103};
    int n = idx >> 7, k = idx & 127;
    int K = Kt[mat], M = Mt[mat];
    float w = (k < K && n < M) ? Wt[mat][(size_t)k * M + n] : 0.f;
    ushort16 h = f2bf(w);
    float lo = w - bf2f(h);
    Whi[(size_t)mat * 16384 + idx] = h;
    Wlo[(size_t)mat * 16384 + idx] = f2bf(lo);
}

// ---------------- bf16 CSR pre-aggregation (layers 1-3) ----------------
template<int UNROLL>
__global__ __launch_bounds__(256) void aggregate_pre_kernel(
    const ushort16* __restrict__ h,
    const int* __restrict__ row_ptr, const int* __restrict__ csr,
    const float* __restrict__ degf, ushort16* __restrict__ aggH, int N) {
    int wid = threadIdx.x >> 6;
    int lane = threadIdx.x & 63;
    int node = blockIdx.x * 4 + wid;
    if (node >= N) return;
    int s = row_ptr[node], e = row_ptr[node + 1];
    int c = lane & 15;
    int eo = lane >> 4;
    float aLo[4] = {}, aHi[4] = {};
    int j = s + eo;
    for (; j + (UNROLL - 1) * 4 < e; j += UNROLL * 4) {
        uint4 v[UNROLL];
#pragma unroll
        for (int u = 0; u < UNROLL; ++u) {
            int src_n = csr[j + u * 4];
            v[u] = *(const uint4*)(h + ((size_t)src_n << 7) + (c << 3));
        }
#pragma unroll
        for (int u = 0; u < UNROLL; ++u) {
            uint32 w[4] = {v[u].x, v[u].y, v[u].z, v[u].w};
#pragma unroll
            for (int p = 0; p < 4; ++p) {
                aLo[p] += __builtin_bit_cast(float, w[p] << 16);
                aHi[p] += __builtin_bit_cast(float, w[p] & 0xffff0000u);
            }
        }
    }
    for (; j < e; j += 4) {
        int src_n = csr[j];
        uint4 v = *(const uint4*)(h + ((size_t)src_n << 7) + (c << 3));
        uint32 w[4] = {v.x, v.y, v.z, v.w};
#pragma unroll
        for (int p = 0; p < 4; ++p) {
            aLo[p] += __builtin_bit_cast(float, w[p] << 16);
            aHi[p] += __builtin_bit_cast(float, w[p] & 0xffff0000u);
        }
    }
#pragma unroll
    for (int m = 16; m < 64; m <<= 1) {
#pragma unroll
        for (int p = 0; p < 4; ++p) {
            aLo[p] += __shfl_xor(aLo[p], m, 64);
            aHi[p] += __shfl_xor(aHi[p], m, 64);
        }
    }
    if (lane < 16) {
        float inv = 1.f / degf[node];
        uint4 ov;
        ov.x = (uint32)f2bf(aLo[0] * inv) | ((uint32)f2bf(aHi[0] * inv) << 16);
        ov.y = (uint32)f2bf(aLo[1] * inv) | ((uint32)f2bf(aHi[1] * inv) << 16);
        ov.z = (uint32)f2bf(aLo[2] * inv) | ((uint32)f2bf(aHi[2] * inv) << 16);
        ov.w = (uint32)f2bf(aLo[3] * inv) | ((uint32)f2bf(aHi[3] * inv) << 16);
        *(uint4*)(aggH + ((size_t)node << 7) + (c << 3)) = ov;
    }
}

// ---------------- fused MFMA layer (layers 1-3), v4 ----------------
// out = bf16( relu( h@Ws + aggH@Wn + bias ) ).
// R10 post-mortem: 256-row blocks -> only 391 blocks (1.5/CU), 180 VGPR,
// Occupancy 8.3% — barrier drains had nothing to overlap with. v4 shrinks
// the tile the OTHER way: 64 rows x 64 cols, grid 1563x2 = 3126 blocks
// (12/CU queued), LDS 20KB (8 blocks/CU), acc = 16 VGPR (~80 total, ~6
// waves/SIMD) -> ~6 co-resident blocks per CU to overlap barriers. Total
// LDS-read + staging traffic per output unchanged vs R8; A/G read 2x
// (+50MB/layer from L2/L3, a few us).
#define RS 40   // LDS row stride in ushorts (80B, 16B-aligned, bank-spread)
__global__ __launch_bounds__(256) void mfma_fused_kernel(
    const ushort16* __restrict__ A, const ushort16* __restrict__ G,
    const ushort16* __restrict__ Whi, const ushort16* __restrict__ Wlo,
    const float* __restrict__ bias,
    ushort16* __restrict__ Out, int N, int M) {
    __shared__ ushort16 Bs[4][64 * RS];
    const int tid = threadIdx.x;
    const int wave = tid >> 6;
    const int lane = tid & 63;
    const int quad = lane >> 4;
    const int m16 = lane & 15;
    // [0]=Ws_hi, [1]=Ws_lo, [2]=Wn_hi, [3]=Wn_lo
    const ushort16* Wg[4] = {Whi, Wlo, Whi + 16384, Wlo + 16384};

    floatx4 acc[4] = {};                    // 4 n-tiles of 16 cols

    const int n0 = blockIdx.y * 64;         // this block's column half
    int rowA = blockIdx.x * 64 + wave * 16 + m16;
    if (rowA >= N) rowA = N - 1;            // clamp: stores guarded below
    const ushort16* Arow = A + (size_t)rowA * 128;
    const ushort16* Grow = G + (size_t)rowA * 128;

    const int sn = tid >> 2, sh = tid & 3;  // staging: row n (64), 16B quarter
    for (int k0 = 0; k0 < 128; k0 += 32) {
#pragma unroll
        for (int mat = 0; mat < 4; ++mat) {
            const ushort16* g = Wg[mat] + (size_t)(n0 + sn) * 128 + k0 + sh * 8;
            *(uint4*)(&Bs[mat][sn * RS + sh * 8]) = *(const uint4*)g;
        }
        short8 af = *(const short8*)(Arow + k0 + quad * 8);
        short8 gf = *(const short8*)(Grow + k0 + quad * 8);
        __syncthreads();
#pragma unroll
        for (int t = 0; t < 4; ++t) {
            int nb = t * 16 + m16;
            short8 bsh = *(const short8*)(&Bs[0][nb * RS + quad * 8]);
            short8 bsl = *(const short8*)(&Bs[1][nb * RS + quad * 8]);
            short8 bnh = *(const short8*)(&Bs[2][nb * RS + quad * 8]);
            short8 bnl = *(const short8*)(&Bs[3][nb * RS + quad * 8]);
            acc[t] = __builtin_amdgcn_mfma_f32_16x16x32_bf16(af, bsh, acc[t], 0, 0, 0);
            acc[t] = __builtin_amdgcn_mfma_f32_16x16x32_bf16(gf, bnh, acc[t], 0, 0, 0);
            acc[t] = __builtin_amdgcn_mfma_f32_16x16x32_bf16(af, bsl, acc[t], 0, 0, 0);
            acc[t] = __builtin_amdgcn_mfma_f32_16x16x32_bf16(gf, bnl, acc[t], 0, 0, 0);
        }
        __syncthreads();
    }

    // D layout: row = quad*4 + reg, col = n0 + t*16 + m16
    int rowBase = blockIdx.x * 64 + wave * 16 + quad * 4;
#pragma unroll
    for (int t = 0; t < 4; ++t) {
        int colt = n0 + t * 16 + m16;
        bool inc = (colt < M);
        float b = inc ? bias[colt] : 0.f;
#pragma unroll
        for (int r = 0; r < 4; ++r) {
            int row = rowBase + r;
            if (row < N) {
                float v = inc ? fmaxf(acc[t][r] + b, 0.f) : 0.f;
                Out[(size_t)row * 128 + colt] = f2bf(v);
            }
        }
    }
}

// ---------------- layer 4: tiny GEMM (M=5) ----------------
__global__ __launch_bounds__(256) void gemm4_kernel(
    const ushort16* __restrict__ A, const float* __restrict__ ws,
    const float* __restrict__ wn, const float* __restrict__ b4,
    float* __restrict__ Cs, float* __restrict__ Cn, int N, int K, int M) {
    __shared__ float Wsh[520], Wnh[520];
    int tid = threadIdx.x;
    for (int i = tid; i < K * M; i += 256) { Wsh[i] = ws[i]; Wnh[i] = wn[i]; }
    __syncthreads();
    int node = blockIdx.x * 256 + tid;
    if (node >= N) return;
    const ushort16* row = A + ((size_t)node << 7);
    float s[5] = {}, n[5] = {};
    for (int c8 = 0; c8 * 8 < K; ++c8) {
        uint4 v = *(const uint4*)(row + c8 * 8);
        uint32 w[4] = {v.x, v.y, v.z, v.w};
#pragma unroll
        for (int j = 0; j < 8; ++j) {
            int k = c8 * 8 + j;
            if (k < K) {
                float a = (j & 1) ? __builtin_bit_cast(float, w[j >> 1] & 0xffff0000u)
                                  : __builtin_bit_cast(float, w[j >> 1] << 16);
#pragma unroll
                for (int m = 0; m < 5; ++m) {
                    s[m] += a * Wsh[k * 5 + m];
                    n[m] += a * Wnh[k * 5 + m];
                }
            }
        }
    }
    size_t o = (size_t)node * 8;
#pragma unroll
    for (int m = 0; m < 5; ++m) {
        Cs[o + m] = s[m] + b4[m];
        Cn[o + m] = n[m];
    }
#pragma unroll
    for (int m = 5; m < 8; ++m) { Cs[o + m] = 0.f; Cn[o + m] = 0.f; }
}

// ---------------- fp32 CSR aggregation (layer 4, stride 8) ----------------
template<int CPW, int UNROLL, int SLOG>
__global__ __launch_bounds__(256) void aggregate_fp32_kernel(
    const float* __restrict__ hs, const float* __restrict__ hn,
    const int* __restrict__ row_ptr, const int* __restrict__ csr,
    const float* __restrict__ degf, float* __restrict__ out, int N) {
    constexpr int EPI = 64 / CPW;
    int wid = threadIdx.x >> 6;
    int lane = threadIdx.x & 63;
    int node = blockIdx.x * 4 + wid;
    if (node >= N) return;
    int s = row_ptr[node], e = row_ptr[node + 1];
    int c = lane & (CPW - 1);
    int eo = lane / CPW;
    float4 acc = make_float4(0.f, 0.f, 0.f, 0.f);
    int j = s + eo;
    for (; j + (UNROLL - 1) * EPI < e; j += UNROLL * EPI) {
        float4 v[UNROLL];
#pragma unroll
        for (int u = 0; u < UNROLL; ++u) {
            int src_n = csr[j + u * EPI];
            v[u] = *(const float4*)(hn + ((size_t)src_n << SLOG) + (c << 2));
        }
#pragma unroll
        for (int u = 0; u < UNROLL; ++u) {
            acc.x += v[u].x; acc.y += v[u].y; acc.z += v[u].z; acc.w += v[u].w;
        }
    }
    for (; j < e; j += EPI) {
        int src_n = csr[j];
        float4 v = *(const float4*)(hn + ((size_t)src_n << SLOG) + (c << 2));
        acc.x += v.x; acc.y += v.y; acc.z += v.z; acc.w += v.w;
    }
#pragma unroll
    for (int m = CPW; m < 64; m <<= 1) {
        acc.x += __shfl_xor(acc.x, m, 64);
        acc.y += __shfl_xor(acc.y, m, 64);
        acc.z += __shfl_xor(acc.z, m, 64);
        acc.w += __shfl_xor(acc.w, m, 64);
    }
    if (lane < CPW) {
        float d = 1.f / degf[node];
        size_t o = ((size_t)node << SLOG) + (lane << 2);
        float4 hv = *(const float4*)(hs + o);
        float4 r;
        r.x = hv.x + acc.x * d;
        r.y = hv.y + acc.y * d;
        r.z = hv.z + acc.z * d;
        r.w = hv.w + acc.w * d;
        *(float4*)(out + o) = r;
    }
}

// ---------------- per-graph mean pool (stride 8) ----------------
__global__ __launch_bounds__(256) void pool_kernel(
    const float* __restrict__ h, float* __restrict__ out, int npg) {
    __shared__ float sh[4][5];
    int g = blockIdx.x;
    int t = threadIdx.x;
    float acc[5] = {0.f, 0.f, 0.f, 0.f, 0.f};
    int base = g * npg;
    for (int i = t; i < npg; i += 256) {
        const float* r = h + ((size_t)(base + i) << 3);
#pragma unroll
        for (int f = 0; f < 5; ++f) acc[f] += r[f];
    }
#pragma unroll
    for (int off = 32; off > 0; off >>= 1) {
#pragma unroll
        for (int f = 0; f < 5; ++f) acc[f] += __shfl_down(acc[f], off, 64);
    }
    int wid = t >> 6, lane = t & 63;
    if (lane == 0) {
#pragma unroll
        for (int f = 0; f < 5; ++f) sh[wid][f] = acc[f];
    }
    __syncthreads();
    if (t == 0) {
        float inv = 1.f / (float)npg;
#pragma unroll
        for (int f = 0; f < 5; ++f)
            out[g * 5 + f] = (sh[0][f] + sh[1][f] + sh[2][f] + sh[3][f]) * inv;
    }
}

extern "C" void kernel_launch(void* const* d_in, const int* in_sizes, int n_in,
                              void* d_out, int out_size, void* d_ws, size_t ws_size,
                              hipStream_t stream) {
    const float* in_feat = (const float*)d_in[0];
    const int* src = (const int*)d_in[1];
    const int* dst = (const int*)d_in[2];
    const int DIMS[5] = {128, 128, 118, 103, 5};
    const int N = in_sizes[0] / 128;
    const int E = in_sizes[1];
    const int G = out_size / 5;
    const int NBUCK = (N + 255) >> 8;   // 256-node dst buckets (<=512 for LDS)

    char* base = (char*)d_ws;
    size_t off = 0;
    auto carve = [&](size_t bytes) -> void* {
        off = (off + 255) & ~(size_t)255;
        void* p = base + off;
        off += bytes;
        return p;
    };
    int* bcnt = (int*)carve((size_t)NBUCK * 4);
    int* bucketOff = (int*)carve((size_t)(NBUCK + 1) * 4);
    int* cursorA = (int*)carve((size_t)NBUCK * 4);
    int* row_ptr = (int*)carve((size_t)(N + 1) * 4);
    float* degf = (float*)carve((size_t)N * 4);
    uint32* ebuf = (uint32*)carve((size_t)E * 4);
    int* csr = (int*)carve((size_t)E * 4);
    ushort16* buf0 = (ushort16*)carve((size_t)(N + 256) * 128 * 2);
    ushort16* buf1 = (ushort16*)carve((size_t)(N + 256) * 128 * 2);
    ushort16* aggH = (ushort16*)carve((size_t)(N + 256) * 128 * 2);
    ushort16* Whi = (ushort16*)carve((size_t)6 * 16384 * 2);
    ushort16* Wlo = (ushort16*)carve((size_t)6 * 16384 * 2);
    float* Cs4 = (float*)carve((size_t)N * 8 * 4);
    float* Cn4 = (float*)carve((size_t)N * 8 * 4);
    float* out4 = (float*)carve((size_t)N * 8 * 4);
    (void)n_in; (void)ws_size;

    // graph structure: bucket sizes -> offsets -> partition -> per-bucket build
    hipMemsetAsync(bcnt, 0, (size_t)NBUCK * 4, stream);
    bucket_hist_kernel<<<(E + PBS - 1) / PBS, 256, 0, stream>>>(dst, bcnt, E, NBUCK);
    bucket_scan_kernel<<<1, 256, 0, stream>>>(bcnt, bucketOff, cursorA, NBUCK, E);
    bucket_partition_kernel<<<(E + PBS - 1) / PBS, 256, 0, stream>>>(
        src, dst, cursorA, ebuf, E, NBUCK);
    bucket_build_kernel<<<NBUCK, 256, 0, stream>>>(
        ebuf, bucketOff, row_ptr, degf, csr, N, E);

    // dtype prep
    int n8 = N * 16;   // N*128/8
    conv_bf16_kernel<<<(n8 + 255) / 256, 256, 0, stream>>>(in_feat, buf0, n8);
    prep_w_all_kernel<<<6 * 64, 256, 0, stream>>>(
        (const float*)d_in[4], (const float*)d_in[5],
        (const float*)d_in[7], (const float*)d_in[8],
        (const float*)d_in[10], (const float*)d_in[11],
        Whi, Wlo);

    // layers 1-3: aggregate-first, then fused MFMA (64x64 tiles, grid x2 cols)
    ushort16* hb[4] = {buf0, buf1, buf0, buf1};
    dim3 ggrid((N + 63) / 64, 2);
    for (int l = 0; l < 3; ++l) {
        int M = DIMS[l + 1];
        const float* b = (const float*)d_in[6 + 3 * l];
        aggregate_pre_kernel<4><<<(N + 3) / 4, 256, 0, stream>>>(
            hb[l], row_ptr, csr, degf, aggH, N);
        mfma_fused_kernel<<<ggrid, 256, 0, stream>>>(
            hb[l], aggH, Whi + (size_t)l * 2 * 16384, Wlo + (size_t)l * 2 * 16384,
            b, hb[l + 1], N, M);
    }

    // layer 4 (aggregate-after: dout=5) + pool
    gemm4_kernel<<<(N + 255) / 256, 256, 0, stream>>>(
        hb[3], (const float*)d_in[13], (const float*)d_in[14], (const float*)d_in[15],
        Cs4, Cn4, N, DIMS[3], DIMS[4]);
    aggregate_fp32_kernel<2, 1, 3><<<(N + 3) / 4, 256, 0, stream>>>(
        Cs4, Cn4, row_ptr, csr, degf, out4, N);
    pool_kernel<<<G, 256, 0, stream>>>(out4, (float*)d_out, N / G);
}